// Round 7
// baseline (58.314 us; speedup 1.0000x reference)
//
#include <hip/hip_runtime.h>
#include <math.h>

#define HW   (224 * 224)
#define TXW 32
#define HX 34
#define CH 8                    // output rows per block
#define NROWS 10                // resident halo rows (rel 0..9 = gy-1..gy+8)
#define NPXH (HX * NROWS)       // 340 pixels
#define UN_A (HX * 6 * 8)       // 1632 units: rows rel 0..5
#define UN_B (HX * 4 * 8)       // 1088 units: rows rel 6..9
#define BPI (28 * 7)            // 196 blocks per image

typedef __attribute__((ext_vector_type(8))) short bf16x8;
typedef __attribute__((ext_vector_type(4))) float f32x4;

__device__ __forceinline__ unsigned bf16rne(float f) {
  unsigned u = __float_as_uint(f);
  u += 0x7fffu + ((u >> 16) & 1u);
  return u >> 16;
}
__device__ __forceinline__ unsigned cvt_pk_bf16(float lo, float hi) {
  unsigned r;
  asm("v_cvt_pk_bf16_f32 %0, %1, %2" : "=v"(r) : "v"(lo), "v"(hi));
  return r;
}
#define LOG2E 1.4426950408889634f

// ---------------------------------------------------------------------------
// kpack: blocks 0..8: B fragments, layout wb[(kk*64+lane)*2 + pass] (uint4);
// pass0 = bf16(w), pass1 = bf16(w - fp32(bf16(w))). Block 9: wwv.
// ---------------------------------------------------------------------------
__global__ __launch_bounds__(256) void kpack(
    const float* __restrict__ w1, const float* __restrict__ w2,
    const float* __restrict__ w3, const float* __restrict__ w4,
    const float* __restrict__ w5, unsigned short* __restrict__ wb,
    float* __restrict__ wwv)
{
  const int tid = threadIdx.x;
  const int bid = blockIdx.x;
  if (bid == 9) {
    if (tid < 64) {
      const int lane = tid;
      float pw0=0.f, pw1=0.f, pw2=0.f, pw3=0.f;
      for (int it = 0; it < 9; ++it) {
        const int d = lane + it*64;
        const float v0=w3[d*4+0], v1=w3[d*4+1], v2=w3[d*4+2], v3=w3[d*4+3];
        pw0=fmaf(v0,v0,pw0); pw1=fmaf(v1,v1,pw1);
        pw2=fmaf(v2,v2,pw2); pw3=fmaf(v3,v3,pw3);
      }
      for (int off = 32; off > 0; off >>= 1) {
        pw0 += __shfl_down(pw0,off); pw1 += __shfl_down(pw1,off);
        pw2 += __shfl_down(pw2,off); pw3 += __shfl_down(pw3,off);
      }
      if (lane == 0) { wwv[0]=pw0; wwv[1]=pw1; wwv[2]=pw2; wwv[3]=pw3; }
    }
    return;
  }
  const int item = bid*256 + tid;        // 0..2303
  const int pass = item / 1152;
  const int rem  = item - pass*1152;
  const int kk   = rem >> 6;
  const int l    = rem & 63;
  const int col  = l & 15, kg = l >> 4;
  unsigned short hs[8];
#pragma unroll
  for (int i = 0; i < 8; ++i) {
    const int k = kk*32 + kg*8 + i;
    const int s = k >> 6, c = k & 63;
    const int d = c*9 + s;
    float v = (col==0) ? w1[d] : (col==1) ? w2[d] :
              (col<6)  ? w3[d*4 + (col-2)] :
              (col<11) ? w4[d*5 + (col-6)] : w5[d*5 + (col-11)];
    unsigned hb = bf16rne(v);
    if (pass) {
      const float r = v - __uint_as_float(hb << 16);
      hb = bf16rne(r);
    }
    hs[i] = (unsigned short)hb;
  }
  uint4 pk;
  pk.x = hs[0] | ((unsigned)hs[1] << 16);
  pk.y = hs[2] | ((unsigned)hs[3] << 16);
  pk.z = hs[4] | ((unsigned)hs[5] << 16);
  pk.w = hs[6] | ((unsigned)hs[7] << 16);
  ((uint4*)wb)[(kk*64 + l)*2 + pass] = pk;
}

// ---------------------------------------------------------------------------
// kmain: 256 thr, 32x8 output chunk = 2 sub-tiles of 32x4 sharing a flat
// 10-row halo (rel rows 0..9). Rows 6..9 global-loaded to regs at entry
// (issue-early), ds_written after sub-tile-0 compute (write-late) -> staging
// latency hidden under MFMA. XOR-swizzled bf16 LDS; hi/lo split weights.
// NOTE: B prefetch queue (bq) is (re)initialized INSIDE compute_subtile —
// a by-reference stale queue across the two calls was R6's correctness bug.
// ---------------------------------------------------------------------------
__global__ __launch_bounds__(256, 3) void kmain(
    const float* __restrict__ x, const unsigned short* __restrict__ wb,
    const float* __restrict__ wwv, const float* __restrict__ gpt,
    const float* __restrict__ c4p, const float* __restrict__ c5p,
    float* __restrict__ out)
{
  __shared__ __align__(16) uint4 xl16[NPXH * 8];   // 43520 B
  __shared__ float s2l[NPXH];                      // 1360 B
  __shared__ float xxl[TXW * 4];                   // 512 B

  const int tid = threadIdx.x;
  const int bid = blockIdx.x;
  const int b   = bid / BPI;
  const int t   = bid - b*BPI;
  const int ch  = t / 7;
  const int txi = t - ch*7;
  const int y0  = ch * CH;
  const int x0  = txi * TXW;
  const float* __restrict__ xb = x + (size_t)b * HW * 64;

  const int lane   = tid & 63;
  const int wv     = tid >> 6;
  const int colsel = lane & 15;
  const int kg     = lane >> 4;

  // ---- Issue-early: global loads for rows rel 6..9 (gy = y0+5..y0+8) ----
  float4 pva[5], pvb[5];
#pragma unroll
  for (int i = 0; i < 5; ++i) {
    pva[i] = make_float4(0.f,0.f,0.f,0.f);
    pvb[i] = make_float4(0.f,0.f,0.f,0.f);
    const int item = tid + i*256;
    if (item < UN_B) {
      const int px = item >> 3, u = item & 7;
      const int hy = px / HX, hx = px - hy*HX;
      const int gy = y0 + 5 + hy;
      const int gx = x0 + hx - 1;
      if (gy < 224 && (unsigned)gx < 224u) {
        const float* src = xb + ((size_t)gy*224 + gx)*64 + u*8;
        pva[i] = *(const float4*)src;
        pvb[i] = *(const float4*)(src + 4);
      }
    }
  }

  // ---- Phase A: stage rows rel 0..5 ----
  for (int item = tid; item < UN_A; item += 256) {
    const int px = item >> 3, u = item & 7;
    const int hy = px / HX, hx = px - hy*HX;
    const int gy = y0 - 1 + hy;
    const int gx = x0 + hx - 1;
    float4 va = make_float4(0.f,0.f,0.f,0.f);
    float4 vb = make_float4(0.f,0.f,0.f,0.f);
    if ((unsigned)gy < 224u && (unsigned)gx < 224u) {
      const float* src = xb + ((size_t)gy*224 + gx)*64 + u*8;
      va = *(const float4*)src;
      vb = *(const float4*)(src + 4);
    }
    float p2 = fmaf(va.x,va.x, fmaf(va.y,va.y, fmaf(va.z,va.z, va.w*va.w)));
    p2 = fmaf(vb.x,vb.x, fmaf(vb.y,vb.y, fmaf(vb.z,vb.z, fmaf(vb.w,vb.w, p2))));
    p2 += __shfl_xor(p2, 1);
    p2 += __shfl_xor(p2, 2);
    p2 += __shfl_xor(p2, 4);
    uint4 pk;
    pk.x = cvt_pk_bf16(va.x, va.y);
    pk.y = cvt_pk_bf16(va.z, va.w);
    pk.z = cvt_pk_bf16(vb.x, vb.y);
    pk.w = cvt_pk_bf16(vb.z, vb.w);
    xl16[px*8 + (u ^ (px & 7))] = pk;
    if (u == 0) s2l[px] = p2;
  }
  __syncthreads();

  const bf16x8* __restrict__ wbv = (const bf16x8*)wb;
  const float g = gpt[0], cc4 = c4p[0], cc5 = c5p[0];
  const float ek = -g * LOG2E;
  const float wwsel = (colsel >= 2 && colsel < 6) ? wwv[colsel - 2] : 0.f;

  // Compute one 32x4 sub-tile (s = 0 or 1) from halo rows s*4 .. s*4+5.
  auto compute_subtile = [&](int s) {
    // Fresh B prefetch queue each call (kk=0,1; both passes).
    bf16x8 bq[2][2];
    bq[0][0] = wbv[(0*64 + lane)*2 + 0];
    bq[0][1] = wbv[(0*64 + lane)*2 + 1];
    bq[1][0] = wbv[(1*64 + lane)*2 + 0];
    bq[1][1] = wbv[(1*64 + lane)*2 + 1];

    f32x4 acc0 = (f32x4){0.f,0.f,0.f,0.f};
    f32x4 acc1 = (f32x4){0.f,0.f,0.f,0.f};
    const int pxr = (s*4 + wv)*HX + colsel;   // tile row = wv; halves at +0,+16
#pragma unroll
    for (int kk = 0; kk < 18; ++kk) {
      const bf16x8 cb0 = bq[kk & 1][0];
      const bf16x8 cb1 = bq[kk & 1][1];
      if (kk < 16) {
        bq[kk & 1][0] = wbv[((kk+2)*64 + lane)*2 + 0];
        bq[kk & 1][1] = wbv[((kk+2)*64 + lane)*2 + 1];
      }
      const int s9 = kk >> 1;
      const int ky = s9 / 3, kx = s9 - ky*3;
      const int u  = (kk & 1)*4 + kg;
      const int pxA = pxr + ky*HX + kx;
      const int pxB = pxA + 16;
      const bf16x8 a0 = *(const bf16x8*)&xl16[pxA*8 + (u ^ (pxA & 7))];
      const bf16x8 a1 = *(const bf16x8*)&xl16[pxB*8 + (u ^ (pxB & 7))];
      acc0 = __builtin_amdgcn_mfma_f32_16x16x32_bf16(a0, cb0, acc0, 0, 0, 0);
      acc1 = __builtin_amdgcn_mfma_f32_16x16x32_bf16(a1, cb0, acc1, 0, 0, 0);
      acc0 = __builtin_amdgcn_mfma_f32_16x16x32_bf16(a0, cb1, acc0, 0, 0, 0);
      acc1 = __builtin_amdgcn_mfma_f32_16x16x32_bf16(a1, cb1, acc1, 0, 0, 0);
    }
    const int gy = y0 + s*4 + wv;
#pragma unroll
    for (int j = 0; j < 2; ++j) {
      const int xh = j*16;
      float rv[4], xr[4];
#pragma unroll
      for (int r = 0; r < 4; ++r) {
        rv[r] = (j == 0) ? acc0[r] : acc1[r];
        xr[r] = xxl[wv*TXW + xh + kg*4 + r];
      }
      if (colsel == 1) {
#pragma unroll
        for (int r = 0; r < 4; ++r) {
          const float a = fminf(fmaxf(rv[r], -30.f), 30.f);
          const float e2 = __builtin_exp2f(a * (2.f*LOG2E));
          rv[r] = 1.f - 2.f*__builtin_amdgcn_rcpf(e2 + 1.f);
        }
      } else if (colsel >= 2 && colsel < 6) {
#pragma unroll
        for (int r = 0; r < 4; ++r)
          rv[r] = __builtin_exp2f(ek * (xr[r] - 2.f*rv[r] + wwsel));
      } else if (colsel >= 6 && colsel < 11) {
#pragma unroll
        for (int r = 0; r < 4; ++r) { const float uq = rv[r] + cc4; rv[r] = uq*uq*uq; }
      } else if (colsel >= 11) {
#pragma unroll
        for (int r = 0; r < 4; ++r) { const float uq = rv[r] + cc5; const float q = uq*uq; rv[r] = q*q*uq; }
      }
#pragma unroll
      for (int r = 0; r < 4; ++r) {
        const int gx = x0 + xh + kg*4 + r;
        out[(((size_t)b*224 + gy)*224 + gx)*16 + colsel] = rv[r];
      }
    }
  };

  // ---- box-sum for sub-tile 0 (halo rows 0..5) ----
  if (tid < 128) {
    const int ox = tid & 31, oy = tid >> 5;
    float s = 0.f;
#pragma unroll
    for (int dy = 0; dy < 3; ++dy)
#pragma unroll
      for (int dx = 0; dx < 3; ++dx)
        s += s2l[(oy+dy)*HX + ox+dx];
    xxl[tid] = s;
  }
  __syncthreads();

  compute_subtile(0);

  // ---- Write-late: rows rel 6..9 from prefetched regs -> LDS ----
#pragma unroll
  for (int i = 0; i < 5; ++i) {
    const int item = tid + i*256;
    if (item < UN_B) {
      const int px = item >> 3, u = item & 7;
      const int hy = px / HX, hx = px - hy*HX;
      const int lpx = (6 + hy)*HX + hx;
      float p2 = fmaf(pva[i].x,pva[i].x, fmaf(pva[i].y,pva[i].y,
                 fmaf(pva[i].z,pva[i].z, pva[i].w*pva[i].w)));
      p2 = fmaf(pvb[i].x,pvb[i].x, fmaf(pvb[i].y,pvb[i].y,
           fmaf(pvb[i].z,pvb[i].z, fmaf(pvb[i].w,pvb[i].w, p2))));
      p2 += __shfl_xor(p2, 1);
      p2 += __shfl_xor(p2, 2);
      p2 += __shfl_xor(p2, 4);
      uint4 pk;
      pk.x = cvt_pk_bf16(pva[i].x, pva[i].y);
      pk.y = cvt_pk_bf16(pva[i].z, pva[i].w);
      pk.z = cvt_pk_bf16(pvb[i].x, pvb[i].y);
      pk.w = cvt_pk_bf16(pvb[i].z, pvb[i].w);
      xl16[lpx*8 + (u ^ (lpx & 7))] = pk;
      if (u == 0) s2l[lpx] = p2;
    }
  }
  __syncthreads();

  // ---- box-sum for sub-tile 1 (halo rows 4..9) ----
  if (tid < 128) {
    const int ox = tid & 31, oy = tid >> 5;
    float s = 0.f;
#pragma unroll
    for (int dy = 0; dy < 3; ++dy)
#pragma unroll
      for (int dx = 0; dx < 3; ++dx)
        s += s2l[(4+oy+dy)*HX + ox+dx];
    xxl[tid] = s;
  }
  __syncthreads();

  compute_subtile(1);
}

extern "C" void kernel_launch(void* const* d_in, const int* in_sizes, int n_in,
                              void* d_out, int out_size, void* d_ws, size_t ws_size,
                              hipStream_t stream) {
  const float* x  = (const float*)d_in[0];
  const float* w1 = (const float*)d_in[1];
  const float* w2 = (const float*)d_in[2];
  const float* w3 = (const float*)d_in[3];
  const float* w4 = (const float*)d_in[4];
  const float* w5 = (const float*)d_in[5];
  const float* g  = (const float*)d_in[6];
  const float* c4 = (const float*)d_in[7];
  const float* c5 = (const float*)d_in[8];
  float* out = (float*)d_out;

  unsigned short* wb = (unsigned short*)d_ws;   // 2304 uint4 = 36864 B
  float* wwv = (float*)((char*)d_ws + 36864);   // 4 floats

  kpack<<<10, 256, 0, stream>>>(w1, w2, w3, w4, w5, wb, wwv);
  kmain<<<8 * BPI, 256, 0, stream>>>(x, wb, wwv, g, c4, c5, out);
}

// Round 8
// 52.892 us; speedup vs baseline: 1.1025x; 1.1025x over previous
//
#include <hip/hip_runtime.h>
#include <math.h>

#define HW   (224 * 224)
#define TXW 32
#define TYH 4
#define HX 34
#define HY 6
#define NPXH (HX * HY)          // 204 halo pixels
#define NUNIT (NPXH * 8)        // 1632 16B-units to stage
#define BPI ((224 / TYH) * (224 / TXW))   // 392 blocks per image

typedef __attribute__((ext_vector_type(8))) short bf16x8;
typedef __attribute__((ext_vector_type(4))) float f32x4;

__device__ __forceinline__ unsigned bf16rne(float f) {
  unsigned u = __float_as_uint(f);
  u += 0x7fffu + ((u >> 16) & 1u);
  return u >> 16;
}
__device__ __forceinline__ unsigned cvt_pk_bf16(float lo, float hi) {
  unsigned r;
  asm("v_cvt_pk_bf16_f32 %0, %1, %2" : "=v"(r) : "v"(lo), "v"(hi));
  return r;
}
#define LOG2E 1.4426950408889634f

// ---------------------------------------------------------------------------
// kpack: blocks 0..8: B fragments, layout wb[(kk*64+lane)*2 + pass] (uint4);
// pass0 = bf16(w), pass1 = bf16(w - fp32(bf16(w))). Block 9: wwv.
// ---------------------------------------------------------------------------
__global__ __launch_bounds__(256) void kpack(
    const float* __restrict__ w1, const float* __restrict__ w2,
    const float* __restrict__ w3, const float* __restrict__ w4,
    const float* __restrict__ w5, unsigned short* __restrict__ wb,
    float* __restrict__ wwv)
{
  const int tid = threadIdx.x;
  const int bid = blockIdx.x;
  if (bid == 9) {
    if (tid < 64) {
      const int lane = tid;
      float pw0=0.f, pw1=0.f, pw2=0.f, pw3=0.f;
      for (int it = 0; it < 9; ++it) {
        const int d = lane + it*64;
        const float v0=w3[d*4+0], v1=w3[d*4+1], v2=w3[d*4+2], v3=w3[d*4+3];
        pw0=fmaf(v0,v0,pw0); pw1=fmaf(v1,v1,pw1);
        pw2=fmaf(v2,v2,pw2); pw3=fmaf(v3,v3,pw3);
      }
      for (int off = 32; off > 0; off >>= 1) {
        pw0 += __shfl_down(pw0,off); pw1 += __shfl_down(pw1,off);
        pw2 += __shfl_down(pw2,off); pw3 += __shfl_down(pw3,off);
      }
      if (lane == 0) { wwv[0]=pw0; wwv[1]=pw1; wwv[2]=pw2; wwv[3]=pw3; }
    }
    return;
  }
  const int item = bid*256 + tid;        // 0..2303
  const int pass = item / 1152;
  const int rem  = item - pass*1152;
  const int kk   = rem >> 6;
  const int l    = rem & 63;
  const int col  = l & 15, kg = l >> 4;
  unsigned short hs[8];
#pragma unroll
  for (int i = 0; i < 8; ++i) {
    const int k = kk*32 + kg*8 + i;
    const int s = k >> 6, c = k & 63;
    const int d = c*9 + s;
    float v = (col==0) ? w1[d] : (col==1) ? w2[d] :
              (col<6)  ? w3[d*4 + (col-2)] :
              (col<11) ? w4[d*5 + (col-6)] : w5[d*5 + (col-11)];
    unsigned hb = bf16rne(v);
    if (pass) {
      const float r = v - __uint_as_float(hb << 16);
      hb = bf16rne(r);
    }
    hs[i] = (unsigned short)hb;
  }
  uint4 pk;
  pk.x = hs[0] | ((unsigned)hs[1] << 16);
  pk.y = hs[2] | ((unsigned)hs[3] << 16);
  pk.z = hs[4] | ((unsigned)hs[5] << 16);
  pk.w = hs[6] | ((unsigned)hs[7] << 16);
  ((uint4*)wb)[(kk*64 + l)*2 + pass] = pk;
}

// ---------------------------------------------------------------------------
// kmain: 256 thr (4 waves), tile 32x4, halo 34x6 bf16 in LDS, XOR swizzle.
// Changes vs R5: (1) staging loop is compile-time 7-unrolled (predicated) so
// the compiler can hoist/overlap the global loads; (2) xx box-sum kept in
// registers per wave (lanes 0..31) + __shfl in epilogue -> no xxl array, one
// barrier fewer, LDS 26928 B -> 6 blocks/CU; (3) launch_bounds(256,6).
// ---------------------------------------------------------------------------
__global__ __launch_bounds__(256, 6) void kmain(
    const float* __restrict__ x, const unsigned short* __restrict__ wb,
    const float* __restrict__ wwv, const float* __restrict__ gpt,
    const float* __restrict__ c4p, const float* __restrict__ c5p,
    float* __restrict__ out)
{
  __shared__ __align__(16) uint4 xl16[NPXH * 8];   // 26112 B
  __shared__ float s2l[NPXH];                      // 816 B

  const int tid = threadIdx.x;
  const int bid = blockIdx.x;
  const int b   = bid / BPI;
  const int t   = bid - b*BPI;
  const int tyi = t / 7;
  const int txi = t - tyi*7;
  const int y0  = tyi * TYH;
  const int x0  = txi * TXW;
  const float* __restrict__ xb = x + (size_t)b * HW * 64;

  const int lane   = tid & 63;
  const int wv     = tid >> 6;
  const int colsel = lane & 15;
  const int kg     = lane >> 4;

  // ---- Stage halo -> bf16 LDS (swizzled) + per-pixel sum(x^2) ----
  // Compile-time trip count (7) so the compiler can pipeline the loads.
#pragma unroll
  for (int i = 0; i < 7; ++i) {
    const int item = tid + i*256;
    if (item < NUNIT) {
      const int px = item >> 3, u = item & 7;
      const int hy = px / HX, hx = px - hy*HX;
      const int gy = y0 + hy - 1;
      const int gx = x0 + hx - 1;
      float4 va = make_float4(0.f,0.f,0.f,0.f);
      float4 vb = make_float4(0.f,0.f,0.f,0.f);
      if ((unsigned)gy < 224u && (unsigned)gx < 224u) {
        const float* src = xb + ((size_t)gy*224 + gx)*64 + u*8;
        va = *(const float4*)src;
        vb = *(const float4*)(src + 4);
      }
      float p2 = fmaf(va.x,va.x, fmaf(va.y,va.y, fmaf(va.z,va.z, va.w*va.w)));
      p2 = fmaf(vb.x,vb.x, fmaf(vb.y,vb.y, fmaf(vb.z,vb.z, fmaf(vb.w,vb.w, p2))));
      p2 += __shfl_xor(p2, 1);
      p2 += __shfl_xor(p2, 2);
      p2 += __shfl_xor(p2, 4);
      uint4 pk;
      pk.x = cvt_pk_bf16(va.x, va.y);
      pk.y = cvt_pk_bf16(va.z, va.w);
      pk.z = cvt_pk_bf16(vb.x, vb.y);
      pk.w = cvt_pk_bf16(vb.z, vb.w);
      xl16[px*8 + (u ^ (px & 7))] = pk;
      if (u == 0) s2l[px] = p2;
    }
  }
  __syncthreads();

  // ---- Per-wave xx box-sum into registers (wave wv owns output row wv) ----
  const int bcol = lane & 31;
  float xxv = 0.f;
#pragma unroll
  for (int dy = 0; dy < 3; ++dy)
#pragma unroll
    for (int dx = 0; dx < 3; ++dx)
      xxv += s2l[(wv + dy)*HX + bcol + dx];

  // ---- MFMA K-loop: row wv, two 16-px halves ----
  const bf16x8* __restrict__ wbv = (const bf16x8*)wb;
  bf16x8 bq00 = wbv[(0*64 + lane)*2 + 0];
  bf16x8 bq01 = wbv[(0*64 + lane)*2 + 1];
  bf16x8 bq10 = wbv[(1*64 + lane)*2 + 0];
  bf16x8 bq11 = wbv[(1*64 + lane)*2 + 1];

  f32x4 acc0 = (f32x4){0.f,0.f,0.f,0.f};
  f32x4 acc1 = (f32x4){0.f,0.f,0.f,0.f};
  const int pxr = wv*HX + colsel;

#pragma unroll
  for (int kk = 0; kk < 18; ++kk) {
    const bf16x8 cb0 = (kk & 1) ? bq10 : bq00;
    const bf16x8 cb1 = (kk & 1) ? bq11 : bq01;
    if (kk < 16) {
      if (kk & 1) {
        bq10 = wbv[((kk+2)*64 + lane)*2 + 0];
        bq11 = wbv[((kk+2)*64 + lane)*2 + 1];
      } else {
        bq00 = wbv[((kk+2)*64 + lane)*2 + 0];
        bq01 = wbv[((kk+2)*64 + lane)*2 + 1];
      }
    }
    const int s9 = kk >> 1;
    const int ky = s9 / 3, kx = s9 - ky*3;
    const int u  = (kk & 1)*4 + kg;
    const int pxA = pxr + ky*HX + kx;
    const int pxB = pxA + 16;
    const bf16x8 a0 = *(const bf16x8*)&xl16[pxA*8 + (u ^ (pxA & 7))];
    const bf16x8 a1 = *(const bf16x8*)&xl16[pxB*8 + (u ^ (pxB & 7))];
    acc0 = __builtin_amdgcn_mfma_f32_16x16x32_bf16(a0, cb0, acc0, 0, 0, 0);
    acc1 = __builtin_amdgcn_mfma_f32_16x16x32_bf16(a1, cb0, acc1, 0, 0, 0);
    acc0 = __builtin_amdgcn_mfma_f32_16x16x32_bf16(a0, cb1, acc0, 0, 0, 0);
    acc1 = __builtin_amdgcn_mfma_f32_16x16x32_bf16(a1, cb1, acc1, 0, 0, 0);
  }

  // ---- Epilogue: D layout col=lane&15, row=kg*4+r ----
  const float g = gpt[0], cc4 = c4p[0], cc5 = c5p[0];
  const float ek = -g * LOG2E;
  const float wwsel = (colsel >= 2 && colsel < 6) ? wwv[colsel - 2] : 0.f;
  const int gy = y0 + wv;

#pragma unroll
  for (int j = 0; j < 2; ++j) {
    const int xh = j*16;
    float rv[4], xr[4];
#pragma unroll
    for (int r = 0; r < 4; ++r) {
      rv[r] = (j == 0) ? acc0[r] : acc1[r];
      xr[r] = __shfl(xxv, xh + kg*4 + r);
    }
    if (colsel == 1) {
#pragma unroll
      for (int r = 0; r < 4; ++r) {
        const float a = fminf(fmaxf(rv[r], -30.f), 30.f);
        const float e2 = __builtin_exp2f(a * (2.f*LOG2E));
        rv[r] = 1.f - 2.f*__builtin_amdgcn_rcpf(e2 + 1.f);
      }
    } else if (colsel >= 2 && colsel < 6) {
#pragma unroll
      for (int r = 0; r < 4; ++r)
        rv[r] = __builtin_exp2f(ek * (xr[r] - 2.f*rv[r] + wwsel));
    } else if (colsel >= 6 && colsel < 11) {
#pragma unroll
      for (int r = 0; r < 4; ++r) { const float uq = rv[r] + cc4; rv[r] = uq*uq*uq; }
    } else if (colsel >= 11) {
#pragma unroll
      for (int r = 0; r < 4; ++r) { const float uq = rv[r] + cc5; const float q = uq*uq; rv[r] = q*q*uq; }
    }
#pragma unroll
    for (int r = 0; r < 4; ++r) {
      const int gx = x0 + xh + kg*4 + r;
      out[(((size_t)b*224 + gy)*224 + gx)*16 + colsel] = rv[r];
    }
  }
}

extern "C" void kernel_launch(void* const* d_in, const int* in_sizes, int n_in,
                              void* d_out, int out_size, void* d_ws, size_t ws_size,
                              hipStream_t stream) {
  const float* x  = (const float*)d_in[0];
  const float* w1 = (const float*)d_in[1];
  const float* w2 = (const float*)d_in[2];
  const float* w3 = (const float*)d_in[3];
  const float* w4 = (const float*)d_in[4];
  const float* w5 = (const float*)d_in[5];
  const float* g  = (const float*)d_in[6];
  const float* c4 = (const float*)d_in[7];
  const float* c5 = (const float*)d_in[8];
  float* out = (float*)d_out;

  unsigned short* wb = (unsigned short*)d_ws;   // 2304 uint4 = 36864 B
  float* wwv = (float*)((char*)d_ws + 36864);   // 4 floats

  kpack<<<10, 256, 0, stream>>>(w1, w2, w3, w4, w5, wb, wwv);
  kmain<<<8 * BPI, 256, 0, stream>>>(x, wb, wwv, g, c4, c5, out);
}

// Round 9
// 45.272 us; speedup vs baseline: 1.2881x; 1.1683x over previous
//
#include <hip/hip_runtime.h>
#include <math.h>

#define HW   (224 * 224)
#define TXW 32
#define TYH 4
#define HX 34
#define HY 6
#define NPXH (HX * HY)          // 204 halo pixels
#define NUNIT (NPXH * 8)        // 1632 16B-units to stage
#define BPI ((224 / TYH) * (224 / TXW))   // 392 blocks per image

typedef __attribute__((ext_vector_type(8))) short bf16x8;
typedef __attribute__((ext_vector_type(4))) float f32x4;

__device__ __forceinline__ unsigned bf16rne(float f) {
  unsigned u = __float_as_uint(f);
  u += 0x7fffu + ((u >> 16) & 1u);
  return u >> 16;
}
__device__ __forceinline__ unsigned cvt_pk_bf16(float lo, float hi) {
  unsigned r;
  asm("v_cvt_pk_bf16_f32 %0, %1, %2" : "=v"(r) : "v"(lo), "v"(hi));
  return r;
}
#define LOG2E 1.4426950408889634f

// ---------------------------------------------------------------------------
// kpack: blocks 0..4: single-pass bf16 B fragments, wb[kk*64+lane] (uint4),
// 1152 items. Block 5: wwv[j] = sum_d w3[d][j]^2.
// ---------------------------------------------------------------------------
__global__ __launch_bounds__(256) void kpack(
    const float* __restrict__ w1, const float* __restrict__ w2,
    const float* __restrict__ w3, const float* __restrict__ w4,
    const float* __restrict__ w5, unsigned short* __restrict__ wb,
    float* __restrict__ wwv)
{
  const int tid = threadIdx.x;
  const int bid = blockIdx.x;
  if (bid == 5) {
    if (tid < 64) {
      const int lane = tid;
      float pw0=0.f, pw1=0.f, pw2=0.f, pw3=0.f;
      for (int it = 0; it < 9; ++it) {
        const int d = lane + it*64;
        const float v0=w3[d*4+0], v1=w3[d*4+1], v2=w3[d*4+2], v3=w3[d*4+3];
        pw0=fmaf(v0,v0,pw0); pw1=fmaf(v1,v1,pw1);
        pw2=fmaf(v2,v2,pw2); pw3=fmaf(v3,v3,pw3);
      }
      for (int off = 32; off > 0; off >>= 1) {
        pw0 += __shfl_down(pw0,off); pw1 += __shfl_down(pw1,off);
        pw2 += __shfl_down(pw2,off); pw3 += __shfl_down(pw3,off);
      }
      if (lane == 0) { wwv[0]=pw0; wwv[1]=pw1; wwv[2]=pw2; wwv[3]=pw3; }
    }
    return;
  }
  const int item = bid*256 + tid;        // 0..1151
  if (item >= 1152) return;
  const int kk   = item >> 6;
  const int l    = item & 63;
  const int col  = l & 15, kg = l >> 4;
  unsigned short hs[8];
#pragma unroll
  for (int i = 0; i < 8; ++i) {
    const int k = kk*32 + kg*8 + i;
    const int s = k >> 6, c = k & 63;
    const int d = c*9 + s;
    float v = (col==0) ? w1[d] : (col==1) ? w2[d] :
              (col<6)  ? w3[d*4 + (col-2)] :
              (col<11) ? w4[d*5 + (col-6)] : w5[d*5 + (col-11)];
    hs[i] = (unsigned short)bf16rne(v);
  }
  uint4 pk;
  pk.x = hs[0] | ((unsigned)hs[1] << 16);
  pk.y = hs[2] | ((unsigned)hs[3] << 16);
  pk.z = hs[4] | ((unsigned)hs[5] << 16);
  pk.w = hs[6] | ((unsigned)hs[7] << 16);
  ((uint4*)wb)[kk*64 + l] = pk;
}

// ---------------------------------------------------------------------------
// kmain: 256 thr (4 waves), tile 32x4, halo 34x6 bf16 in LDS, XOR swizzle.
// Single-pass bf16 weights: B working set 18 KB (L1-resident), K-loop is
// 18 x {1 B-load (3-deep prefetch), 2 ds_read_b128, 2 MFMA}.
// xx box-sum in registers + __shfl epilogue. 6 blocks/CU.
// ---------------------------------------------------------------------------
__global__ __launch_bounds__(256, 6) void kmain(
    const float* __restrict__ x, const unsigned short* __restrict__ wb,
    const float* __restrict__ wwv, const float* __restrict__ gpt,
    const float* __restrict__ c4p, const float* __restrict__ c5p,
    float* __restrict__ out)
{
  __shared__ __align__(16) uint4 xl16[NPXH * 8];   // 26112 B
  __shared__ float s2l[NPXH];                      // 816 B

  const int tid = threadIdx.x;
  const int bid = blockIdx.x;
  const int b   = bid / BPI;
  const int t   = bid - b*BPI;
  const int tyi = t / 7;
  const int txi = t - tyi*7;
  const int y0  = tyi * TYH;
  const int x0  = txi * TXW;
  const float* __restrict__ xb = x + (size_t)b * HW * 64;

  const int lane   = tid & 63;
  const int wv     = tid >> 6;
  const int colsel = lane & 15;
  const int kg     = lane >> 4;

  // ---- Stage halo -> bf16 LDS (swizzled) + per-pixel sum(x^2) ----
#pragma unroll
  for (int i = 0; i < 7; ++i) {
    const int item = tid + i*256;
    if (item < NUNIT) {
      const int px = item >> 3, u = item & 7;
      const int hy = px / HX, hx = px - hy*HX;
      const int gy = y0 + hy - 1;
      const int gx = x0 + hx - 1;
      float4 va = make_float4(0.f,0.f,0.f,0.f);
      float4 vb = make_float4(0.f,0.f,0.f,0.f);
      if ((unsigned)gy < 224u && (unsigned)gx < 224u) {
        const float* src = xb + ((size_t)gy*224 + gx)*64 + u*8;
        va = *(const float4*)src;
        vb = *(const float4*)(src + 4);
      }
      float p2 = fmaf(va.x,va.x, fmaf(va.y,va.y, fmaf(va.z,va.z, va.w*va.w)));
      p2 = fmaf(vb.x,vb.x, fmaf(vb.y,vb.y, fmaf(vb.z,vb.z, fmaf(vb.w,vb.w, p2))));
      p2 += __shfl_xor(p2, 1);
      p2 += __shfl_xor(p2, 2);
      p2 += __shfl_xor(p2, 4);
      uint4 pk;
      pk.x = cvt_pk_bf16(va.x, va.y);
      pk.y = cvt_pk_bf16(va.z, va.w);
      pk.z = cvt_pk_bf16(vb.x, vb.y);
      pk.w = cvt_pk_bf16(vb.z, vb.w);
      xl16[px*8 + (u ^ (px & 7))] = pk;
      if (u == 0) s2l[px] = p2;
    }
  }
  __syncthreads();

  // ---- Per-wave xx box-sum into registers (wave wv owns output row wv) ----
  const int bcol = lane & 31;
  float xxv = 0.f;
#pragma unroll
  for (int dy = 0; dy < 3; ++dy)
#pragma unroll
    for (int dx = 0; dx < 3; ++dx)
      xxv += s2l[(wv + dy)*HX + bcol + dx];

  // ---- MFMA K-loop: row wv, two 16-px halves; 3-deep B prefetch ----
  const bf16x8* __restrict__ wbv = (const bf16x8*)wb;
  bf16x8 bq0 = wbv[0*64 + lane];
  bf16x8 bq1 = wbv[1*64 + lane];
  bf16x8 bq2 = wbv[2*64 + lane];

  f32x4 acc0 = (f32x4){0.f,0.f,0.f,0.f};
  f32x4 acc1 = (f32x4){0.f,0.f,0.f,0.f};
  const int pxr = wv*HX + colsel;

#pragma unroll
  for (int kk = 0; kk < 18; ++kk) {
    const int ring = kk % 3;
    const bf16x8 cb = (ring == 0) ? bq0 : (ring == 1) ? bq1 : bq2;
    if (kk < 15) {
      if (ring == 0)      bq0 = wbv[(kk+3)*64 + lane];
      else if (ring == 1) bq1 = wbv[(kk+3)*64 + lane];
      else                bq2 = wbv[(kk+3)*64 + lane];
    }
    const int s9 = kk >> 1;
    const int ky = s9 / 3, kx = s9 - ky*3;
    const int u  = (kk & 1)*4 + kg;
    const int pxA = pxr + ky*HX + kx;
    const int pxB = pxA + 16;
    const bf16x8 a0 = *(const bf16x8*)&xl16[pxA*8 + (u ^ (pxA & 7))];
    const bf16x8 a1 = *(const bf16x8*)&xl16[pxB*8 + (u ^ (pxB & 7))];
    acc0 = __builtin_amdgcn_mfma_f32_16x16x32_bf16(a0, cb, acc0, 0, 0, 0);
    acc1 = __builtin_amdgcn_mfma_f32_16x16x32_bf16(a1, cb, acc1, 0, 0, 0);
  }

  // ---- Epilogue: D layout col=lane&15, row=kg*4+r ----
  const float g = gpt[0], cc4 = c4p[0], cc5 = c5p[0];
  const float ek = -g * LOG2E;
  const float wwsel = (colsel >= 2 && colsel < 6) ? wwv[colsel - 2] : 0.f;
  const int gy = y0 + wv;

#pragma unroll
  for (int j = 0; j < 2; ++j) {
    const int xh = j*16;
    float rv[4], xr[4];
#pragma unroll
    for (int r = 0; r < 4; ++r) {
      rv[r] = (j == 0) ? acc0[r] : acc1[r];
      xr[r] = __shfl(xxv, xh + kg*4 + r);
    }
    if (colsel == 1) {
#pragma unroll
      for (int r = 0; r < 4; ++r) {
        const float a = fminf(fmaxf(rv[r], -30.f), 30.f);
        const float e2 = __builtin_exp2f(a * (2.f*LOG2E));
        rv[r] = 1.f - 2.f*__builtin_amdgcn_rcpf(e2 + 1.f);
      }
    } else if (colsel >= 2 && colsel < 6) {
#pragma unroll
      for (int r = 0; r < 4; ++r)
        rv[r] = __builtin_exp2f(ek * (xr[r] - 2.f*rv[r] + wwsel));
    } else if (colsel >= 6 && colsel < 11) {
#pragma unroll
      for (int r = 0; r < 4; ++r) { const float uq = rv[r] + cc4; rv[r] = uq*uq*uq; }
    } else if (colsel >= 11) {
#pragma unroll
      for (int r = 0; r < 4; ++r) { const float uq = rv[r] + cc5; const float q = uq*uq; rv[r] = q*q*uq; }
    }
#pragma unroll
    for (int r = 0; r < 4; ++r) {
      const int gx = x0 + xh + kg*4 + r;
      out[(((size_t)b*224 + gy)*224 + gx)*16 + colsel] = rv[r];
    }
  }
}

extern "C" void kernel_launch(void* const* d_in, const int* in_sizes, int n_in,
                              void* d_out, int out_size, void* d_ws, size_t ws_size,
                              hipStream_t stream) {
  const float* x  = (const float*)d_in[0];
  const float* w1 = (const float*)d_in[1];
  const float* w2 = (const float*)d_in[2];
  const float* w3 = (const float*)d_in[3];
  const float* w4 = (const float*)d_in[4];
  const float* w5 = (const float*)d_in[5];
  const float* g  = (const float*)d_in[6];
  const float* c4 = (const float*)d_in[7];
  const float* c5 = (const float*)d_in[8];
  float* out = (float*)d_out;

  unsigned short* wb = (unsigned short*)d_ws;   // 1152 uint4 = 18432 B
  float* wwv = (float*)((char*)d_ws + 18432);   // 4 floats

  kpack<<<6, 256, 0, stream>>>(w1, w2, w3, w4, w5, wb, wwv);
  kmain<<<8 * BPI, 256, 0, stream>>>(x, wb, wwv, g, c4, c5, out);
}

// Round 10
// 44.812 us; speedup vs baseline: 1.3013x; 1.0103x over previous
//
#include <hip/hip_runtime.h>
#include <math.h>

#define HW   (224 * 224)
#define TXW 32
#define TYH 4
#define HX 34
#define HY 6
#define NPXH (HX * HY)          // 204 halo pixels
#define NUNIT (NPXH * 8)        // 1632 16B-units to stage
#define BPI ((224 / TYH) * (224 / TXW))   // 392 blocks per image

typedef __attribute__((ext_vector_type(8))) short bf16x8;
typedef __attribute__((ext_vector_type(4))) float f32x4;

__device__ __forceinline__ unsigned bf16rne(float f) {
  unsigned u = __float_as_uint(f);
  u += 0x7fffu + ((u >> 16) & 1u);
  return u >> 16;
}
__device__ __forceinline__ unsigned cvt_pk_bf16(float lo, float hi) {
  unsigned r;
  asm("v_cvt_pk_bf16_f32 %0, %1, %2" : "=v"(r) : "v"(lo), "v"(hi));
  return r;
}
#define LOG2E 1.4426950408889634f

// ---------------------------------------------------------------------------
// kpack: blocks 0..4: single-pass bf16 B fragments, wb[kk*64+lane] (uint4),
// 1152 items. Block 5: wwv[j] = sum_d w3[d][j]^2.
// ---------------------------------------------------------------------------
__global__ __launch_bounds__(256) void kpack(
    const float* __restrict__ w1, const float* __restrict__ w2,
    const float* __restrict__ w3, const float* __restrict__ w4,
    const float* __restrict__ w5, unsigned short* __restrict__ wb,
    float* __restrict__ wwv)
{
  const int tid = threadIdx.x;
  const int bid = blockIdx.x;
  if (bid == 5) {
    if (tid < 64) {
      const int lane = tid;
      float pw0=0.f, pw1=0.f, pw2=0.f, pw3=0.f;
      for (int it = 0; it < 9; ++it) {
        const int d = lane + it*64;
        const float v0=w3[d*4+0], v1=w3[d*4+1], v2=w3[d*4+2], v3=w3[d*4+3];
        pw0=fmaf(v0,v0,pw0); pw1=fmaf(v1,v1,pw1);
        pw2=fmaf(v2,v2,pw2); pw3=fmaf(v3,v3,pw3);
      }
      for (int off = 32; off > 0; off >>= 1) {
        pw0 += __shfl_down(pw0,off); pw1 += __shfl_down(pw1,off);
        pw2 += __shfl_down(pw2,off); pw3 += __shfl_down(pw3,off);
      }
      if (lane == 0) { wwv[0]=pw0; wwv[1]=pw1; wwv[2]=pw2; wwv[3]=pw3; }
    }
    return;
  }
  const int item = bid*256 + tid;        // 0..1151
  if (item >= 1152) return;
  const int kk   = item >> 6;
  const int l    = item & 63;
  const int col  = l & 15, kg = l >> 4;
  unsigned short hs[8];
#pragma unroll
  for (int i = 0; i < 8; ++i) {
    const int k = kk*32 + kg*8 + i;
    const int s = k >> 6, c = k & 63;
    const int d = c*9 + s;
    float v = (col==0) ? w1[d] : (col==1) ? w2[d] :
              (col<6)  ? w3[d*4 + (col-2)] :
              (col<11) ? w4[d*5 + (col-6)] : w5[d*5 + (col-11)];
    hs[i] = (unsigned short)bf16rne(v);
  }
  uint4 pk;
  pk.x = hs[0] | ((unsigned)hs[1] << 16);
  pk.y = hs[2] | ((unsigned)hs[3] << 16);
  pk.z = hs[4] | ((unsigned)hs[5] << 16);
  pk.w = hs[6] | ((unsigned)hs[7] << 16);
  ((uint4*)wb)[kk*64 + l] = pk;
}

// ---------------------------------------------------------------------------
// kmain: 256 thr (4 waves), tile 32x4, halo 34x6 bf16 in LDS, XOR swizzle.
// R10 deltas vs R9: B-ring preload at entry; 1-deep A-fragment software
// pipeline in K-loop; incremental hy/hx staging addressing (6 + tail);
// s_setprio around K-loop; non-temporal output stores. VGPR must stay <=80
// for 6 waves/SIMD.
// ---------------------------------------------------------------------------
__global__ __launch_bounds__(256, 6) void kmain(
    const float* __restrict__ x, const unsigned short* __restrict__ wb,
    const float* __restrict__ wwv, const float* __restrict__ gpt,
    const float* __restrict__ c4p, const float* __restrict__ c5p,
    float* __restrict__ out)
{
  __shared__ __align__(16) uint4 xl16[NPXH * 8];   // 26112 B
  __shared__ float s2l[NPXH];                      // 816 B

  const int tid = threadIdx.x;
  const int bid = blockIdx.x;
  const int b   = bid / BPI;
  const int t   = bid - b*BPI;
  const int tyi = t / 7;
  const int txi = t - tyi*7;
  const int y0  = tyi * TYH;
  const int x0  = txi * TXW;
  const float* __restrict__ xb = x + (size_t)b * HW * 64;

  const int lane   = tid & 63;
  const int wv     = tid >> 6;
  const int colsel = lane & 15;
  const int kg     = lane >> 4;

  // ---- B-ring preload at entry: latency hidden under staging ----
  const bf16x8* __restrict__ wbv = (const bf16x8*)wb;
  bf16x8 bq0 = wbv[0*64 + lane];
  bf16x8 bq1 = wbv[1*64 + lane];
  bf16x8 bq2 = wbv[2*64 + lane];

  // ---- Stage halo -> bf16 LDS (swizzled) + per-pixel sum(x^2) ----
  const int u = tid & 7;
  {
    int px = tid >> 3;        // 0..31
    int hy = 0, hx = px;      // px < 34 so hy=0 initially
    auto stage1 = [&](int pxv, int hyv, int hxv) {
      const int gy = y0 + hyv - 1;
      const int gx = x0 + hxv - 1;
      float4 va = make_float4(0.f,0.f,0.f,0.f);
      float4 vb = make_float4(0.f,0.f,0.f,0.f);
      if ((unsigned)gy < 224u && (unsigned)gx < 224u) {
        const float* src = xb + ((size_t)gy*224 + gx)*64 + u*8;
        va = *(const float4*)src;
        vb = *(const float4*)(src + 4);
      }
      float p2 = fmaf(va.x,va.x, fmaf(va.y,va.y, fmaf(va.z,va.z, va.w*va.w)));
      p2 = fmaf(vb.x,vb.x, fmaf(vb.y,vb.y, fmaf(vb.z,vb.z, fmaf(vb.w,vb.w, p2))));
      p2 += __shfl_xor(p2, 1);
      p2 += __shfl_xor(p2, 2);
      p2 += __shfl_xor(p2, 4);
      uint4 pk;
      pk.x = cvt_pk_bf16(va.x, va.y);
      pk.y = cvt_pk_bf16(va.z, va.w);
      pk.z = cvt_pk_bf16(vb.x, vb.y);
      pk.w = cvt_pk_bf16(vb.z, vb.w);
      xl16[pxv*8 + (u ^ (pxv & 7))] = pk;
      if (u == 0) s2l[pxv] = p2;
    };
#pragma unroll
    for (int i = 0; i < 6; ++i) {
      stage1(px, hy, hx);
      px += 32; hx += 32;
      if (hx >= HX) { hx -= HX; ++hy; }
    }
    if (tid < 96) stage1(px, hy, hx);   // items 1536..1631
  }
  __syncthreads();

  // ---- Per-wave xx box-sum into registers (wave wv owns output row wv) ----
  const int bcol = lane & 31;
  float xxv = 0.f;
#pragma unroll
  for (int dy = 0; dy < 3; ++dy)
#pragma unroll
    for (int dx = 0; dx < 3; ++dx)
      xxv += s2l[(wv + dy)*HX + bcol + dx];

  // ---- MFMA K-loop: row wv, two 16-px halves; 3-deep B ring,
  //      1-deep A software pipeline ----
  f32x4 acc0 = (f32x4){0.f,0.f,0.f,0.f};
  f32x4 acc1 = (f32x4){0.f,0.f,0.f,0.f};
  const int pxr = wv*HX + colsel;

  auto aptr = [&](int kk, int half) -> const bf16x8* {
    const int s9 = kk >> 1;
    const int ky = s9 / 3, kx = s9 - ky*3;
    const int uu = (kk & 1)*4 + kg;
    const int px = pxr + ky*HX + kx + half*16;
    return (const bf16x8*)&xl16[px*8 + (uu ^ (px & 7))];
  };

  __builtin_amdgcn_s_setprio(1);
  bf16x8 a0 = *aptr(0, 0);
  bf16x8 a1 = *aptr(0, 1);
#pragma unroll
  for (int kk = 0; kk < 18; ++kk) {
    bf16x8 na0, na1;
    if (kk < 17) { na0 = *aptr(kk+1, 0); na1 = *aptr(kk+1, 1); }
    const int ring = kk % 3;
    const bf16x8 cb = (ring == 0) ? bq0 : (ring == 1) ? bq1 : bq2;
    if (kk < 15) {
      if (ring == 0)      bq0 = wbv[(kk+3)*64 + lane];
      else if (ring == 1) bq1 = wbv[(kk+3)*64 + lane];
      else                bq2 = wbv[(kk+3)*64 + lane];
    }
    acc0 = __builtin_amdgcn_mfma_f32_16x16x32_bf16(a0, cb, acc0, 0, 0, 0);
    acc1 = __builtin_amdgcn_mfma_f32_16x16x32_bf16(a1, cb, acc1, 0, 0, 0);
    a0 = na0; a1 = na1;
  }
  __builtin_amdgcn_s_setprio(0);

  // ---- Epilogue: D layout col=lane&15, row=kg*4+r ----
  const float g = gpt[0], cc4 = c4p[0], cc5 = c5p[0];
  const float ek = -g * LOG2E;
  const float wwsel = (colsel >= 2 && colsel < 6) ? wwv[colsel - 2] : 0.f;
  const int gy = y0 + wv;

#pragma unroll
  for (int j = 0; j < 2; ++j) {
    const int xh = j*16;
    float rv[4], xr[4];
#pragma unroll
    for (int r = 0; r < 4; ++r) {
      rv[r] = (j == 0) ? acc0[r] : acc1[r];
      xr[r] = __shfl(xxv, xh + kg*4 + r);
    }
    if (colsel == 1) {
#pragma unroll
      for (int r = 0; r < 4; ++r) {
        const float a = fminf(fmaxf(rv[r], -30.f), 30.f);
        const float e2 = __builtin_exp2f(a * (2.f*LOG2E));
        rv[r] = 1.f - 2.f*__builtin_amdgcn_rcpf(e2 + 1.f);
      }
    } else if (colsel >= 2 && colsel < 6) {
#pragma unroll
      for (int r = 0; r < 4; ++r)
        rv[r] = __builtin_exp2f(ek * (xr[r] - 2.f*rv[r] + wwsel));
    } else if (colsel >= 6 && colsel < 11) {
#pragma unroll
      for (int r = 0; r < 4; ++r) { const float uq = rv[r] + cc4; rv[r] = uq*uq*uq; }
    } else if (colsel >= 11) {
#pragma unroll
      for (int r = 0; r < 4; ++r) { const float uq = rv[r] + cc5; const float q = uq*uq; rv[r] = q*q*uq; }
    }
#pragma unroll
    for (int r = 0; r < 4; ++r) {
      const int gx = x0 + xh + kg*4 + r;
      __builtin_nontemporal_store(rv[r], &out[(((size_t)b*224 + gy)*224 + gx)*16 + colsel]);
    }
  }
}

extern "C" void kernel_launch(void* const* d_in, const int* in_sizes, int n_in,
                              void* d_out, int out_size, void* d_ws, size_t ws_size,
                              hipStream_t stream) {
  const float* x  = (const float*)d_in[0];
  const float* w1 = (const float*)d_in[1];
  const float* w2 = (const float*)d_in[2];
  const float* w3 = (const float*)d_in[3];
  const float* w4 = (const float*)d_in[4];
  const float* w5 = (const float*)d_in[5];
  const float* g  = (const float*)d_in[6];
  const float* c4 = (const float*)d_in[7];
  const float* c5 = (const float*)d_in[8];
  float* out = (float*)d_out;

  unsigned short* wb = (unsigned short*)d_ws;   // 1152 uint4 = 18432 B
  float* wwv = (float*)((char*)d_ws + 18432);   // 4 floats

  kpack<<<6, 256, 0, stream>>>(w1, w2, w3, w4, w5, wb, wwv);
  kmain<<<8 * BPI, 256, 0, stream>>>(x, wb, wwv, g, c4, c5, out);
}